// Round 11
// baseline (29.540 us; speedup 1.0000x reference)
//
#include <hip/hip_runtime.h>

// ---- problem constants ----
#define IN_C  16
#define OUT_C 32
#define NB 2
#define TT 8
#define DD 8
#define HH 32
#define WW 32
#define TP 10
#define DP 10
#define HP 34
#define WPAD 34

// xt layout: [n][tp][dp][hp][icblk(2)][w(34)][ic8] bf16 ; row = 1088 B
#define XT_ROW_B  1088
#define XT_ELEMS  (NB*TP*DP*HP*2*WPAD*8)     // 3,699,200 bf16 = 7,398,400 B
// wt layout: [tap(84 padded)][icblk(2)][oc(32)][ic8] bf16 ; taps 81..83 zeroed
#define WT_TAPS_P 84
#define WT_ELEMS  (WT_TAPS_P*2*OUT_C*8)      // 43,008 bf16 = 86,016 B

// conv LDS: A only. Slab = 10 rows x 1088 B padded to 768 lines (12,288 B),
// TRIPLE buffered (staged 2 planes ahead). 36,864 B -> 2+ blocks/CU easily.
#define A_SLAB_B 12288

typedef __bf16 bf16x8 __attribute__((ext_vector_type(8)));
typedef float  f32x4  __attribute__((ext_vector_type(4)));
typedef float  f32x16 __attribute__((ext_vector_type(16)));

__device__ __forceinline__ unsigned short f2bf(float f) {
    unsigned int u = __builtin_bit_cast(unsigned int, f);
    u += 0x7fffu + ((u >> 16) & 1u);       // RNE
    return (unsigned short)(u >> 16);
}

__device__ __forceinline__ void gload16(const void* g, void* l) {
    __builtin_amdgcn_global_load_lds(
        (const __attribute__((address_space(1))) unsigned int*)g,
        (__attribute__((address_space(3))) unsigned int*)l, 16, 0, 0);
}

// ---------------- fused prep: xpose rows + halo zeroing + weight xform ----------------
__global__ __launch_bounds__(256) void prep_kernel(const float* __restrict__ x,
                                                   const float* __restrict__ wsrc,
                                                   unsigned short* __restrict__ xt,
                                                   unsigned short* __restrict__ wt) {
    int b = blockIdx.x;
    int tid = threadIdx.x;
    if (b < 4096) {
        __shared__ unsigned short ls[WW * IN_C];   // [w][c], 1 KiB
        int h = b & 31, d = (b >> 5) & 7, t = (b >> 8) & 7, n = b >> 11;
        int c = tid >> 5, w = tid & 31;
        float v0 = x[((((size_t)(n * IN_C + c)     * TT + t) * DD + d) * HH + h) * WW + w];
        float v1 = x[((((size_t)(n * IN_C + c + 8) * TT + t) * DD + d) * HH + h) * WW + w];
        ls[w * 16 + c]     = f2bf(v0);
        ls[w * 16 + c + 8] = f2bf(v1);
        __syncthreads();
        if (tid < 68) {                 // line = blk*34 + wl
            int blk = tid / 34, wl = tid % 34;
            unsigned char* row = (unsigned char*)xt +
                (size_t)(((n * TP + t + 1) * DP + d + 1) * HP + h + 1) * XT_ROW_B;
            f32x4 val = {0.f, 0.f, 0.f, 0.f};
            if (wl != 0 && wl != 33)
                val = *(const f32x4*)((const unsigned char*)ls + (wl - 1) * 32 + blk * 16);
            *(f32x4*)(row + tid * 16) = val;
        }
    } else if (b < 6800) {
        int j = b - 4096;               // 2704 halo rows
        int n, tp, dp, hp;
        if (j < 1360)      { n = j / 680;  int r = j % 680;  tp = (r / 340) * 9; int r2 = r % 340; dp = r2 / 34;       hp = r2 % 34; }
        else if (j < 2448) { int j2 = j - 1360; n = j2 / 544; int r = j2 % 544; tp = 1 + r / 68;  int r3 = r % 68;  dp = (r3 / 34) * 9; hp = r3 % 34; }
        else               { int j3 = j - 2448; n = j3 / 128; int r = j3 % 128; tp = 1 + r / 16;  int r4 = r % 16;  dp = 1 + r4 / 2;   hp = (r4 & 1) * 33; }
        if (tid < 68) {
            unsigned char* row = (unsigned char*)xt +
                (size_t)(((n * TP + tp) * DP + dp) * HP + hp) * XT_ROW_B;
            f32x4 z = {0.f, 0.f, 0.f, 0.f};
            *(f32x4*)(row + tid * 16) = z;
        }
    } else {
        int idx = (b - 6800) * 256 + tid;   // 0..43007
        int tap = idx >> 9;
        int r = idx & 511;
        int icblk = r >> 8, oc = (r >> 3) & 31, i8 = r & 7;
        int ic = icblk * 8 + i8;
        float v = (tap < 81) ? wsrc[(oc * IN_C + ic) * 81 + tap] : 0.0f;
        wt[idx] = f2bf(v);
    }
}

// ---------------- main: 32x32x16 MFMA, B direct-from-global, A triple-buf 2-ahead ----
// block = 4 waves (256 thr), all compute; wave owns 2 h-rows of the 8-row tile.
// Phase p (= tap-plane kt*3+kd): load B(p+1) -> regs (9 global dwordx4, L1-hot),
// stage A(p+2) -> As[(p+2)%3], compute p from As[p%3] (12 ds_read + 18 MFMA),
// vmcnt(3) [only A(p+2) in flight] + barrier. No full drain in the main loop.
__global__ __launch_bounds__(256, 2) void conv_main_kernel(const unsigned short* __restrict__ xt,
                                                           const unsigned short* __restrict__ wt,
                                                           const float* __restrict__ bias,
                                                           float* __restrict__ out) {
    __shared__ __align__(16) unsigned char As[3][A_SLAB_B];   // 36,864 B total

    int bid = blockIdx.x;
    int lb  = (bid & 7) * 64 + (bid >> 3);   // XCD swizzle, bijective (512 % 8 == 0)
    int hb = lb & 3, d = (lb >> 2) & 7, t = (lb >> 5) & 7, n = lb >> 8;
    int h0 = hb * 8;
    int tid  = threadIdx.x;
    int wv   = tid >> 6;               // 0..3, owns output rows 2wv, 2wv+1
    int lane = tid & 63;
    int l31  = lane & 31;
    int kblk = lane >> 5;

    int ab = kblk * 544 + l31 * 16;    // A-frag lane offset within a row
    const unsigned char* wb = (const unsigned char*)wt + kblk * 512 + l31 * 16;

    // plane source address helper (p = kt*3+kd)
    auto asrc = [&](int p) {
        return (const unsigned char*)xt +
            (size_t)(((n * TP + t + p / 3) * DP + d + p % 3) * HP + h0) * XT_ROW_B;
    };

    // ---- prologue: stage A planes 0,1 ; load B plane 0 -> regs ----
    {
        const unsigned char* s0 = asrc(0);
        const unsigned char* s1 = asrc(1);
#pragma unroll
        for (int i = 0; i < 3; ++i) {
            gload16(s0 + (tid + i * 256) * 16, As[0] + (tid + i * 256) * 16);
            gload16(s1 + (tid + i * 256) * 16, As[1] + (tid + i * 256) * 16);
        }
    }
    bf16x8 bf[2][9];
#pragma unroll
    for (int j = 0; j < 9; ++j)
        bf[0][j] = *(const bf16x8*)(wb + (size_t)j * 1024);
    asm volatile("s_waitcnt vmcnt(0)" ::: "memory");
    __syncthreads();

    f32x16 acc[2];
    acc[0] = {}; acc[1] = {};

#pragma unroll
    for (int p = 0; p < 9; ++p) {
        const int cur = p & 1, nxt = cur ^ 1;   // compile-time after unroll

        // ---- 1. B(p+1) -> registers (9 x global_load_dwordx4, L1/L2-hot) ----
        if (p < 8) {
            const unsigned char* bsrc = wb + (size_t)(p + 1) * 9 * 1024;
#pragma unroll
            for (int j = 0; j < 9; ++j)
                bf[nxt][j] = *(const bf16x8*)(bsrc + (size_t)j * 1024);
        }
        // ---- 2. stage A(p+2) -> As[(p+2)%3] ----
        if (p < 7) {
            const unsigned char* src = asrc(p + 2);
            unsigned char* dst = As[(p + 2) % 3];
#pragma unroll
            for (int i = 0; i < 3; ++i)
                gload16(src + (tid + i * 256) * 16, dst + (tid + i * 256) * 16);
        }

        // ---- 3. compute phase p from As[p%3] ----
        const unsigned char* A = As[p % 3];
#pragma unroll
        for (int rr = 0; rr < 4; ++rr) {       // input rows 2wv+rr
#pragma unroll
            for (int kw = 0; kw < 3; ++kw) {
                bf16x8 a = *(const bf16x8*)(A + (2 * wv + rr) * 1088 + ab + kw * 16);
#pragma unroll
                for (int kh = 0; kh < 3; ++kh) {
                    const int m = rr - kh;
                    if (m >= 0 && m < 2)
                        acc[m] = __builtin_amdgcn_mfma_f32_32x32x16_bf16(a, bf[cur][kh * 3 + kw], acc[m], 0, 0, 0);
                }
            }
        }

        // ---- 4. counted wait: A(p+1)+B(p+1) landed, A(p+2) may fly ----
        asm volatile("s_waitcnt vmcnt(3)" ::: "memory");
        __syncthreads();
    }

    // ---- epilogue: col(oc)=l31, row(w)=(reg&3)+8*(reg>>2)+4*kblk ----
    float bsv = bias[l31];
#pragma unroll
    for (int m = 0; m < 2; ++m) {
        int oh = h0 + 2 * wv + m;
        float* obase = out + (((((size_t)n * OUT_C + l31) * TT + t) * DD + d) * HH + oh) * WW;
#pragma unroll
        for (int q = 0; q < 4; ++q) {
            f32x4 v = { acc[m][4 * q + 0] + bsv, acc[m][4 * q + 1] + bsv,
                        acc[m][4 * q + 2] + bsv, acc[m][4 * q + 3] + bsv };
            *(f32x4*)(obase + 8 * q + 4 * kblk) = v;
        }
    }
}

extern "C" void kernel_launch(void* const* d_in, const int* in_sizes, int n_in,
                              void* d_out, int out_size, void* d_ws, size_t ws_size,
                              hipStream_t stream) {
    const float* x    = (const float*)d_in[0];
    const float* wsrc = (const float*)d_in[1];
    const float* bias = (const float*)d_in[2];
    float* out        = (float*)d_out;

    unsigned short* xt = (unsigned short*)d_ws;
    unsigned short* wt = xt + XT_ELEMS;

    prep_kernel<<<4096 + 2704 + 164, 256, 0, stream>>>(x, wsrc, xt, wt);
    conv_main_kernel<<<NB * TT * DD * 4, 256, 0, stream>>>(xt, wt, bias, out);
}

// Round 12
// 27.111 us; speedup vs baseline: 1.0896x; 1.0896x over previous
//
#include <hip/hip_runtime.h>

// ---- problem constants ----
#define IN_C  16
#define OUT_C 32
#define NB 2
#define TT 8
#define DD 8
#define HH 32
#define WW 32
#define TP 10
#define DP 10
#define HP 34
#define WPAD 34

// xt layout: [n][tp][dp][hp][icblk(2)][w(34)][ic8] bf16 ; row = 1088 B
#define XT_ROW_B  1088
#define XT_ELEMS  (NB*TP*DP*HP*2*WPAD*8)     // 3,699,200 bf16 = 7,398,400 B
// wt layout: [tap(84 padded)][icblk(2)][oc(32)][ic8] bf16 ; taps 81..83 zeroed
#define WT_TAPS_P 84
#define WT_ELEMS  (WT_TAPS_P*2*OUT_C*8)      // 43,008 bf16 = 86,016 B

// Wave-private A slab: 4 rows x 1088 B = 4352 B, padded to 320 lines (5120 B)
// so staging is exactly 5 full-wave gload rounds. Double-buffered per wave.
// 4 waves x 2 x 5120 = 40,960 B -> 2 blocks/CU.
#define W_SLAB_B 5120

typedef __bf16 bf16x8 __attribute__((ext_vector_type(8)));
typedef float  f32x4  __attribute__((ext_vector_type(4)));
typedef float  f32x16 __attribute__((ext_vector_type(16)));

__device__ __forceinline__ unsigned short f2bf(float f) {
    unsigned int u = __builtin_bit_cast(unsigned int, f);
    u += 0x7fffu + ((u >> 16) & 1u);       // RNE
    return (unsigned short)(u >> 16);
}

__device__ __forceinline__ void gload16(const void* g, void* l) {
    __builtin_amdgcn_global_load_lds(
        (const __attribute__((address_space(1))) unsigned int*)g,
        (__attribute__((address_space(3))) unsigned int*)l, 16, 0, 0);
}

// ---------------- fused prep: xpose rows + halo zeroing + weight xform ----------------
__global__ __launch_bounds__(256) void prep_kernel(const float* __restrict__ x,
                                                   const float* __restrict__ wsrc,
                                                   unsigned short* __restrict__ xt,
                                                   unsigned short* __restrict__ wt) {
    int b = blockIdx.x;
    int tid = threadIdx.x;
    if (b < 4096) {
        __shared__ unsigned short ls[WW * IN_C];   // [w][c], 1 KiB
        int h = b & 31, d = (b >> 5) & 7, t = (b >> 8) & 7, n = b >> 11;
        int c = tid >> 5, w = tid & 31;
        float v0 = x[((((size_t)(n * IN_C + c)     * TT + t) * DD + d) * HH + h) * WW + w];
        float v1 = x[((((size_t)(n * IN_C + c + 8) * TT + t) * DD + d) * HH + h) * WW + w];
        ls[w * 16 + c]     = f2bf(v0);
        ls[w * 16 + c + 8] = f2bf(v1);
        __syncthreads();
        if (tid < 68) {                 // line = blk*34 + wl
            int blk = tid / 34, wl = tid % 34;
            unsigned char* row = (unsigned char*)xt +
                (size_t)(((n * TP + t + 1) * DP + d + 1) * HP + h + 1) * XT_ROW_B;
            f32x4 val = {0.f, 0.f, 0.f, 0.f};
            if (wl != 0 && wl != 33)
                val = *(const f32x4*)((const unsigned char*)ls + (wl - 1) * 32 + blk * 16);
            *(f32x4*)(row + tid * 16) = val;
        }
    } else if (b < 6800) {
        int j = b - 4096;               // 2704 halo rows
        int n, tp, dp, hp;
        if (j < 1360)      { n = j / 680;  int r = j % 680;  tp = (r / 340) * 9; int r2 = r % 340; dp = r2 / 34;       hp = r2 % 34; }
        else if (j < 2448) { int j2 = j - 1360; n = j2 / 544; int r = j2 % 544; tp = 1 + r / 68;  int r3 = r % 68;  dp = (r3 / 34) * 9; hp = r3 % 34; }
        else               { int j3 = j - 2448; n = j3 / 128; int r = j3 % 128; tp = 1 + r / 16;  int r4 = r % 16;  dp = 1 + r4 / 2;   hp = (r4 & 1) * 33; }
        if (tid < 68) {
            unsigned char* row = (unsigned char*)xt +
                (size_t)(((n * TP + tp) * DP + dp) * HP + hp) * XT_ROW_B;
            f32x4 z = {0.f, 0.f, 0.f, 0.f};
            *(f32x4*)(row + tid * 16) = z;
        }
    } else {
        int idx = (b - 6800) * 256 + tid;   // 0..43007
        int tap = idx >> 9;
        int r = idx & 511;
        int icblk = r >> 8, oc = (r >> 3) & 31, i8 = r & 7;
        int ic = icblk * 8 + i8;
        float v = (tap < 81) ? wsrc[(oc * IN_C + ic) * 81 + tap] : 0.0f;
        wt[idx] = f2bf(v);
    }
}

// ---------------- main: ZERO-BARRIER wave-private pipelines ----------------
// block = 4 waves (256 thr); wave owns output rows (h0+2wv, +1) and a PRIVATE
// dbuf LDS slab holding its 4 needed input rows per plane. No __syncthreads
// anywhere: per phase, a wave issues A(p+1)->own slab + B(p+1)->regs, waits
// vmcnt(14) (A(p)+B(p) landed; the 14 just-issued keep flying), computes
// 12 ds_read + 18 MFMA. 8 independent wave-pipelines per CU.
__global__ __launch_bounds__(256, 2) void conv_main_kernel(const unsigned short* __restrict__ xt,
                                                           const unsigned short* __restrict__ wt,
                                                           const float* __restrict__ bias,
                                                           float* __restrict__ out) {
    __shared__ __align__(16) unsigned char As[4][2][W_SLAB_B];   // 40,960 B

    int bid = blockIdx.x;
    int lb  = (bid & 7) * 64 + (bid >> 3);   // XCD swizzle, bijective (512 % 8 == 0)
    int hb = lb & 3, d = (lb >> 2) & 7, t = (lb >> 5) & 7, n = lb >> 8;
    int h0 = hb * 8;
    int tid  = threadIdx.x;
    int wv   = tid >> 6;               // 0..3, owns output rows h0+2wv, h0+2wv+1
    int lane = tid & 63;
    int l31  = lane & 31;
    int kblk = lane >> 5;

    int ab = kblk * 544 + l31 * 16;    // A-frag lane offset within a row
    const unsigned char* wb = (const unsigned char*)wt + kblk * 512 + l31 * 16;
    const int rowbase = h0 + 2 * wv;   // first input row this wave needs

    // plane p = kt*3+kd source base for this wave's 4 rows
    auto asrc = [&](int p) {
        return (const unsigned char*)xt +
            (size_t)(((n * TP + t + p / 3) * DP + d + p % 3) * HP + rowbase) * XT_ROW_B;
    };

    unsigned char* slab0 = As[wv][0];
    unsigned char* slab1 = As[wv][1];

    // ---- prologue: A(0) -> slab0 (5 gloads), B(0) -> regs (9 loads) ----
    {
        const unsigned char* s = asrc(0);
#pragma unroll
        for (int i = 0; i < 5; ++i)
            gload16(s + (lane + i * 64) * 16, slab0 + (lane + i * 64) * 16);
    }
    bf16x8 bf[2][9];
#pragma unroll
    for (int j = 0; j < 9; ++j)
        bf[0][j] = *(const bf16x8*)(wb + (size_t)j * 1024);

    f32x16 acc[2];
    acc[0] = {}; acc[1] = {};

#pragma unroll
    for (int p = 0; p < 9; ++p) {
        const int cur = p & 1, nxt = cur ^ 1;   // compile-time under full unroll

        if (p < 8) {
            // issue A(p+1) -> other slab (5 gloads) + B(p+1) -> regs (9 loads)
            const unsigned char* s = asrc(p + 1);
            unsigned char* dstS = (p & 1) ? slab0 : slab1;   // slab[(p+1)&1]
#pragma unroll
            for (int i = 0; i < 5; ++i)
                gload16(s + (lane + i * 64) * 16, dstS + (lane + i * 64) * 16);
            const unsigned char* bsrc = wb + (size_t)(p + 1) * 9216;
#pragma unroll
            for (int j = 0; j < 9; ++j)
                bf[nxt][j] = *(const bf16x8*)(bsrc + (size_t)j * 1024);
            // A(p)+B(p) are the oldest; the 14 just-issued stay in flight
            asm volatile("s_waitcnt vmcnt(14)" ::: "memory");
        } else {
            asm volatile("s_waitcnt vmcnt(0)" ::: "memory");
        }
        __builtin_amdgcn_sched_barrier(0);

        const unsigned char* A = (p & 1) ? slab1 : slab0;    // slab[p&1]
#pragma unroll
        for (int rr = 0; rr < 4; ++rr) {       // local input rows 0..3
#pragma unroll
            for (int kw = 0; kw < 3; ++kw) {
                bf16x8 a = *(const bf16x8*)(A + rr * 1088 + ab + kw * 16);
#pragma unroll
                for (int kh = 0; kh < 3; ++kh) {
                    const int m = rr - kh;
                    if (m >= 0 && m < 2)
                        acc[m] = __builtin_amdgcn_mfma_f32_32x32x16_bf16(a, bf[cur][kh * 3 + kw], acc[m], 0, 0, 0);
                }
            }
        }
    }

    // ---- epilogue: col(oc)=l31, row(w)=(reg&3)+8*(reg>>2)+4*kblk ----
    float bsv = bias[l31];
#pragma unroll
    for (int m = 0; m < 2; ++m) {
        int oh = h0 + 2 * wv + m;
        float* obase = out + (((((size_t)n * OUT_C + l31) * TT + t) * DD + d) * HH + oh) * WW;
#pragma unroll
        for (int q = 0; q < 4; ++q) {
            f32x4 v = { acc[m][4 * q + 0] + bsv, acc[m][4 * q + 1] + bsv,
                        acc[m][4 * q + 2] + bsv, acc[m][4 * q + 3] + bsv };
            *(f32x4*)(obase + 8 * q + 4 * kblk) = v;
        }
    }
}

extern "C" void kernel_launch(void* const* d_in, const int* in_sizes, int n_in,
                              void* d_out, int out_size, void* d_ws, size_t ws_size,
                              hipStream_t stream) {
    const float* x    = (const float*)d_in[0];
    const float* wsrc = (const float*)d_in[1];
    const float* bias = (const float*)d_in[2];
    float* out        = (float*)d_out;

    unsigned short* xt = (unsigned short*)d_ws;
    unsigned short* wt = xt + XT_ELEMS;

    prep_kernel<<<4096 + 2704 + 164, 256, 0, stream>>>(x, wsrc, xt, wt);
    conv_main_kernel<<<NB * TT * DD * 4, 256, 0, stream>>>(xt, wt, bias, out);
}